// Round 4
// baseline (137.858 us; speedup 1.0000x reference)
//
#include <hip/hip_runtime.h>
#include <hip/hip_bf16.h>
#include <stdint.h>

// Problem constants (from reference setup_inputs)
#define B_    32
#define C_    256
#define HW_   16384          // 128*128
#define K_TOP 1638           // int(16384 * 0.1)
#define BPB   16             // blocks per batch (512 blocks / 32 batches)

typedef float f32x2 __attribute__((ext_vector_type(2)));
typedef float f32x4 __attribute__((ext_vector_type(4)));

// ---------------------------------------------------------------------------
// Wave-parallel crossing-bin finder. hist has NB bins (NB in {2048, 512});
// finds bin B s.t. suffix_count(B+1) < k <= suffix_count(B).
// Writes *sh_bin = B, *sh_k = k - suffix_count(B+1). ~300 cycles.
// ---------------------------------------------------------------------------
template <int NB>
__device__ __forceinline__ void find_crossing(const uint32_t* hist, int k,
                                              int* sh_bin, int* sh_k, int tid) {
    constexpr int G = NB >> 6;                      // bins per lane (32 or 8)
    if (tid < 64) {
        const int lane = tid;
        uint32_t gs = 0;
        #pragma unroll
        for (int i = 0; i < G; ++i) {
            const int j = (i + lane) & (G - 1);     // rotate to spread banks
            gs += hist[lane * G + j];
        }
        // suffix sum across 64 lanes
        uint32_t s = gs;
        #pragma unroll
        for (int off = 1; off < 64; off <<= 1) {
            uint32_t t = __shfl_down(s, off);
            s += (lane + off < 64) ? t : 0u;
        }
        uint32_t snext = __shfl_down(s, 1);
        if (lane == 63) snext = 0u;
        const bool mine = (s >= (uint32_t)k) && (snext < (uint32_t)k);
        const unsigned long long bal = __ballot(mine);
        const int g = __ffsll(bal) - 1;             // winning group (uniform)
        const uint32_t above_g = __shfl(snext, g);  // count strictly above group g

        // stage 2: suffix scan of the G bins inside group g
        uint32_t hv = (lane < G) ? hist[g * G + lane] : 0u;
        uint32_t s2 = hv;
        #pragma unroll
        for (int off = 1; off < G; off <<= 1) {
            uint32_t t = __shfl_down(s2, off);
            s2 += (lane + off < G) ? t : 0u;
        }
        uint32_t s2next = __shfl_down(s2, 1);
        if (lane >= G - 1) s2next = 0u;
        const bool mine2 = (lane < G) &&
                           (above_g + s2 >= (uint32_t)k) &&
                           (above_g + s2next < (uint32_t)k);
        if (mine2) {
            *sh_bin = g * G + lane;
            *sh_k   = k - (int)(above_g + s2next);
        }
    }
    __syncthreads();
}

// ---------------------------------------------------------------------------
// Fused kernel. 512 blocks x 256 threads.
// Phase 1 (all blocks): scores[b,hw] = |sum_c x[b,c,hw]*w[c] + bias| for this
//   block's 1024 positions. x loads non-temporal (512 MiB stream-once).
// Handoff: per-batch arrival counter; the 16th (last) block of each batch
//   becomes the consumer and computes that batch's exact top-K mean via
//   3-level radix select on the float bit pattern (values in registers).
// ---------------------------------------------------------------------------
__global__ __launch_bounds__(256) void fused_kernel(const float* __restrict__ x,
                                                    const float* __restrict__ w,
                                                    const float* __restrict__ bias,
                                                    float* __restrict__ scores,
                                                    uint32_t* __restrict__ cnt,
                                                    float* __restrict__ out) {
    // ---------------- score phase ----------------
    const uint32_t tid  = blockIdx.x * 256u + threadIdx.x;   // 0 .. 131071
    const uint32_t bi   = tid >> 12;                         // batch (block-uniform)
    const uint32_t p4   = (tid & 4095u) << 2;                // position*4
    const uint32_t toff = bi * (uint32_t)(C_ * HW_) + p4;

    {
        const float* xc = x;                                 // wave-uniform base
        f32x2 a0 = {0.f, 0.f};
        f32x2 a1 = {0.f, 0.f};

        #pragma unroll 8
        for (int c = 0; c < C_; ++c) {
            const f32x4 v  = __builtin_nontemporal_load(
                                 reinterpret_cast<const f32x4*>(xc + toff));
            const float wc = w[c];                           // uniform -> s_load
            const f32x2 wp = {wc, wc};
            f32x2 lo = __builtin_shufflevector(v, v, 0, 1);
            f32x2 hi = __builtin_shufflevector(v, v, 2, 3);
            asm("v_pk_fma_f32 %0, %1, %2, %0" : "+v"(a0) : "v"(lo), "s"(wp));
            asm("v_pk_fma_f32 %0, %1, %2, %0" : "+v"(a1) : "v"(hi), "s"(wp));
            xc += HW_;
        }

        const float bb = bias[0];
        f32x4 o;
        o[0] = fabsf(a0[0] + bb);
        o[1] = fabsf(a0[1] + bb);
        o[2] = fabsf(a1[0] + bb);
        o[3] = fabsf(a1[1] + bb);
        *reinterpret_cast<f32x4*>(scores + (bi * (uint32_t)HW_ + p4)) = o;
    }

    // ---------------- last-block-done handoff ----------------
    __shared__ int      sh_last;
    __shared__ uint32_t hist[2048];
    __shared__ float    sumc[512];
    __shared__ float    red[4];
    __shared__ int      sh_bin, sh_k;

    __syncthreads();                       // all block stores drained (vmcnt0+barrier)
    if (threadIdx.x == 0) {
        __threadfence();                   // release: write back to device scope
        const uint32_t old = atomicAdd(&cnt[bi], 1u);
        sh_last = (old == (uint32_t)(BPB - 1));
    }
    __syncthreads();
    if (!sh_last) return;                  // 15 of 16 blocks exit here

    __threadfence();                       // acquire: invalidate stale caches

    // ---------------- consumer: exact top-K mean for batch bi ----------------
    const int t = threadIdx.x;
    const uint4* sv = reinterpret_cast<const uint4*>(scores) + (size_t)bi * (HW_ / 4);
    uint32_t r[64];
    #pragma unroll
    for (int j = 0; j < 16; ++j) {
        const uint4 q = sv[t + 256 * j];
        r[4*j+0] = q.x; r[4*j+1] = q.y; r[4*j+2] = q.z; r[4*j+3] = q.w;
    }

    #pragma unroll
    for (int i = t; i < 2048; i += 256) hist[i] = 0u;
    __syncthreads();

    // ---- pass A: bits 30:20 ----
    #pragma unroll
    for (int i = 0; i < 64; ++i) atomicAdd(&hist[r[i] >> 20], 1u);
    __syncthreads();
    find_crossing<2048>(hist, K_TOP, &sh_bin, &sh_k, t);
    const uint32_t B1 = (uint32_t)sh_bin;
    const int      k1 = sh_k;
    __syncthreads();

    #pragma unroll
    for (int i = t; i < 2048; i += 256) hist[i] = 0u;
    __syncthreads();

    // ---- pass B: bits 19:9 among prefix-B1; accumulate sum above B1 ----
    float sAbove = 0.f;
    #pragma unroll
    for (int i = 0; i < 64; ++i) {
        const uint32_t u  = r[i];
        const uint32_t b1 = u >> 20;
        if (b1 > B1)       sAbove += __uint_as_float(u);
        else if (b1 == B1) atomicAdd(&hist[(u >> 9) & 2047u], 1u);
    }
    __syncthreads();
    find_crossing<2048>(hist, k1, &sh_bin, &sh_k, t);
    const uint32_t B2 = (uint32_t)sh_bin;
    const int      k2 = sh_k;
    __syncthreads();

    #pragma unroll
    for (int i = t; i < 512; i += 256) { hist[i] = 0u; sumc[i] = 0.f; }
    __syncthreads();

    // ---- pass C: bits 8:0 among prefix-(B1,B2); counts + exact sums ----
    // (all values in a final bin are bit-identical -> float atomics exact)
    #pragma unroll
    for (int i = 0; i < 64; ++i) {
        const uint32_t u = r[i];
        if ((u >> 20) == B1) {
            const uint32_t b2 = (u >> 9) & 2047u;
            if (b2 > B2) sAbove += __uint_as_float(u);
            else if (b2 == B2) {
                const uint32_t b3 = u & 511u;
                atomicAdd(&hist[b3], 1u);
                atomicAdd(&sumc[b3], __uint_as_float(u));
            }
        }
    }
    __syncthreads();
    find_crossing<512>(hist, k2, &sh_bin, &sh_k, t);
    const uint32_t B3 = (uint32_t)sh_bin;
    const int      k3 = sh_k;
    __syncthreads();

    // values strictly above T living in last-level bins > B3
    #pragma unroll
    for (int i = t; i < 512; i += 256) if (i > (int)B3) sAbove += sumc[i];

    // ---- block reduction (4 waves) ----
    #pragma unroll
    for (int off = 32; off > 0; off >>= 1) sAbove += __shfl_down(sAbove, off);
    if ((t & 63) == 0) red[t >> 6] = sAbove;
    __syncthreads();

    if (t == 0) {
        float tot = red[0] + red[1] + red[2] + red[3];
        const float T = __uint_as_float((B1 << 20) | (B2 << 9) | B3);
        out[bi] = (tot + (float)k3 * T) / (float)K_TOP;
    }
}

// ---------------------------------------------------------------------------
extern "C" void kernel_launch(void* const* d_in, const int* in_sizes, int n_in,
                              void* d_out, int out_size, void* d_ws, size_t ws_size,
                              hipStream_t stream) {
    const float* x    = (const float*)d_in[0];   // [32,256,128,128]
    const float* w    = (const float*)d_in[1];   // [1,256,1,1] -> 256 floats
    const float* bias = (const float*)d_in[2];   // [1]
    float*       out  = (float*)d_out;           // [32,1]

    float*    scores = (float*)d_ws;                                  // 2 MiB
    uint32_t* cnt    = (uint32_t*)((char*)d_ws +
                                   (size_t)B_ * HW_ * sizeof(float)); // 128 B

    // cnt must be zero at every call (ws is poisoned 0xAA once, never restored)
    hipMemsetAsync(cnt, 0, B_ * sizeof(uint32_t), stream);
    fused_kernel<<<512, 256, 0, stream>>>(x, w, bias, scores, cnt, out);
}

// Round 5
// 98.648 us; speedup vs baseline: 1.3975x; 1.3975x over previous
//
#include <hip/hip_runtime.h>
#include <hip/hip_bf16.h>
#include <stdint.h>

// Problem constants (from reference setup_inputs)
#define B_    32
#define C_    256
#define HW_   16384          // 128*128
#define K_TOP 1638           // int(16384 * 0.1)

typedef float f32x2 __attribute__((ext_vector_type(2)));
typedef float f32x4 __attribute__((ext_vector_type(4)));

// ---------------------------------------------------------------------------
// Kernel 1: scores[b, hw] = | sum_c x[b,c,hw] * w[c] + bias |
// - x is 512 MiB stream-once data: NON-TEMPORAL loads (no L1/L2/L3 alloc;
//   keeps the 2 MiB scores buffer cache-resident for kernel 2).  [R3: -7 us]
// - unroll 16: 16 outstanding dwordx4 per wave (16 KiB in flight/wave,
//   128 KiB/CU at 8 waves/CU) to saturate the read path.        [R5 change]
// - per-channel advance on the wave-uniform base pointer -> SADDR loads with
//   scalar base increments; w[c] uniform -> s_load; packed FMA via SGPR pair.
// NOTE (R4 post-mortem): do NOT fuse the topk via last-block-done — the
// device-scope release/acquire fences (L2 writeback + invalidate per block)
// cost ~40 us, far more than the 2-kernel launch overhead they'd save.
// ---------------------------------------------------------------------------
__global__ __launch_bounds__(256) void score_kernel(const float* __restrict__ x,
                                                    const float* __restrict__ w,
                                                    const float* __restrict__ bias,
                                                    float* __restrict__ scores) {
    const uint32_t tid  = blockIdx.x * 256u + threadIdx.x;   // 0 .. 131071
    const uint32_t bi   = tid >> 12;                         // batch
    const uint32_t p4   = (tid & 4095u) << 2;                // position*4
    const uint32_t toff = bi * (uint32_t)(C_ * HW_) + p4;    // element offset (fits 32b)

    const float* xc = x;                                     // wave-uniform, advances by HW_
    f32x2 a0 = {0.f, 0.f};
    f32x2 a1 = {0.f, 0.f};

    #pragma unroll 16
    for (int c = 0; c < C_; ++c) {
        const f32x4 v  = __builtin_nontemporal_load(
                             reinterpret_cast<const f32x4*>(xc + toff));
        const float wc = w[c];                               // uniform -> s_load
        const f32x2 wp = {wc, wc};                           // SGPR pair
        f32x2 lo = __builtin_shufflevector(v, v, 0, 1);
        f32x2 hi = __builtin_shufflevector(v, v, 2, 3);
        asm("v_pk_fma_f32 %0, %1, %2, %0" : "+v"(a0) : "v"(lo), "s"(wp));
        asm("v_pk_fma_f32 %0, %1, %2, %0" : "+v"(a1) : "v"(hi), "s"(wp));
        xc += HW_;
    }

    const float bb = bias[0];
    f32x4 o;
    o[0] = fabsf(a0[0] + bb);
    o[1] = fabsf(a0[1] + bb);
    o[2] = fabsf(a1[0] + bb);
    o[3] = fabsf(a1[1] + bb);
    *reinterpret_cast<f32x4*>(scores + (bi * (uint32_t)HW_ + p4)) = o;
}

// ---------------------------------------------------------------------------
// Wave-parallel crossing-bin finder. hist has NB bins (NB in {2048, 512});
// finds bin B s.t. suffix_count(B+1) < k <= suffix_count(B).
// ---------------------------------------------------------------------------
template <int NB>
__device__ __forceinline__ void find_crossing(const uint32_t* hist, int k,
                                              int* sh_bin, int* sh_k, int tid) {
    constexpr int G = NB >> 6;                      // bins per lane (32 or 8)
    if (tid < 64) {
        const int lane = tid;
        uint32_t gs = 0;
        #pragma unroll
        for (int i = 0; i < G; ++i) {
            const int j = (i + lane) & (G - 1);     // rotate to spread banks
            gs += hist[lane * G + j];
        }
        // suffix sum across 64 lanes
        uint32_t s = gs;
        #pragma unroll
        for (int off = 1; off < 64; off <<= 1) {
            uint32_t t = __shfl_down(s, off);
            s += (lane + off < 64) ? t : 0u;
        }
        uint32_t snext = __shfl_down(s, 1);
        if (lane == 63) snext = 0u;
        const bool mine = (s >= (uint32_t)k) && (snext < (uint32_t)k);
        const unsigned long long bal = __ballot(mine);
        const int g = __ffsll(bal) - 1;             // winning group (uniform)
        const uint32_t above_g = __shfl(snext, g);  // count strictly above group g

        // stage 2: suffix scan of the G bins inside group g
        uint32_t hv = (lane < G) ? hist[g * G + lane] : 0u;
        uint32_t s2 = hv;
        #pragma unroll
        for (int off = 1; off < G; off <<= 1) {
            uint32_t t = __shfl_down(s2, off);
            s2 += (lane + off < G) ? t : 0u;
        }
        uint32_t s2next = __shfl_down(s2, 1);
        if (lane >= G - 1) s2next = 0u;
        const bool mine2 = (lane < G) &&
                           (above_g + s2 >= (uint32_t)k) &&
                           (above_g + s2next < (uint32_t)k);
        if (mine2) {
            *sh_bin = g * G + lane;
            *sh_k   = k - (int)(above_g + s2next);
        }
    }
    __syncthreads();
}

// ---------------------------------------------------------------------------
// Kernel 2: per-batch exact top-K mean. One block (1024 thr, 16 waves) per
// batch; each thread keeps 16 values in registers for all 3 radix passes.
// Radix levels: bits 30:20 (2048 bins) -> 19:9 (2048) -> 8:0 (512, counts +
// sums; values in a final bin are bit-identical so float atomics are exact).
// ---------------------------------------------------------------------------
__global__ __launch_bounds__(1024) void topk_mean_kernel(const float* __restrict__ scores,
                                                         float* __restrict__ out) {
    const int tid = threadIdx.x;
    const int b   = blockIdx.x;

    __shared__ uint32_t hist[2048];
    __shared__ float    sumc[512];
    __shared__ float    red[16];
    __shared__ int      sh_bin, sh_k;

    const uint4* sv = reinterpret_cast<const uint4*>(scores) + (size_t)b * (HW_ / 4);
    uint32_t r[16];
    {
        uint4 q;
        q = sv[tid];        r[0]  = q.x; r[1]  = q.y; r[2]  = q.z; r[3]  = q.w;
        q = sv[tid + 1024]; r[4]  = q.x; r[5]  = q.y; r[6]  = q.z; r[7]  = q.w;
        q = sv[tid + 2048]; r[8]  = q.x; r[9]  = q.y; r[10] = q.z; r[11] = q.w;
        q = sv[tid + 3072]; r[12] = q.x; r[13] = q.y; r[14] = q.z; r[15] = q.w;
    }

    hist[tid] = 0u; hist[tid + 1024] = 0u;
    __syncthreads();

    // ---- pass A: bits 30:20 ----
    #pragma unroll
    for (int i = 0; i < 16; ++i) atomicAdd(&hist[r[i] >> 20], 1u);
    __syncthreads();
    find_crossing<2048>(hist, K_TOP, &sh_bin, &sh_k, tid);
    const uint32_t B1 = (uint32_t)sh_bin;
    const int      k1 = sh_k;
    __syncthreads();

    hist[tid] = 0u; hist[tid + 1024] = 0u;
    __syncthreads();

    // ---- pass B: bits 19:9 among prefix-B1; accumulate sum above B1 ----
    float sAbove = 0.f;
    #pragma unroll
    for (int i = 0; i < 16; ++i) {
        const uint32_t u  = r[i];
        const uint32_t b1 = u >> 20;
        if (b1 > B1)       sAbove += __uint_as_float(u);
        else if (b1 == B1) atomicAdd(&hist[(u >> 9) & 2047u], 1u);
    }
    __syncthreads();
    find_crossing<2048>(hist, k1, &sh_bin, &sh_k, tid);
    const uint32_t B2 = (uint32_t)sh_bin;
    const int      k2 = sh_k;
    __syncthreads();

    if (tid < 512) { hist[tid] = 0u; sumc[tid] = 0.f; }
    __syncthreads();

    // ---- pass C: bits 8:0 among prefix-(B1,B2); counts + exact sums ----
    #pragma unroll
    for (int i = 0; i < 16; ++i) {
        const uint32_t u = r[i];
        if ((u >> 20) == B1) {
            const uint32_t b2 = (u >> 9) & 2047u;
            if (b2 > B2) sAbove += __uint_as_float(u);
            else if (b2 == B2) {
                const uint32_t b3 = u & 511u;
                atomicAdd(&hist[b3], 1u);
                atomicAdd(&sumc[b3], __uint_as_float(u));
            }
        }
    }
    __syncthreads();
    find_crossing<512>(hist, k2, &sh_bin, &sh_k, tid);
    const uint32_t B3 = (uint32_t)sh_bin;
    const int      k3 = sh_k;
    __syncthreads();

    if (tid < 512 && tid > (int)B3) sAbove += sumc[tid];

    #pragma unroll
    for (int off = 32; off > 0; off >>= 1) sAbove += __shfl_down(sAbove, off);
    if ((tid & 63) == 0) red[tid >> 6] = sAbove;
    __syncthreads();

    if (tid == 0) {
        float tot = 0.f;
        #pragma unroll
        for (int i = 0; i < 16; ++i) tot += red[i];
        const float T = __uint_as_float((B1 << 20) | (B2 << 9) | B3);
        out[b] = (tot + (float)k3 * T) / (float)K_TOP;
    }
}

// ---------------------------------------------------------------------------
extern "C" void kernel_launch(void* const* d_in, const int* in_sizes, int n_in,
                              void* d_out, int out_size, void* d_ws, size_t ws_size,
                              hipStream_t stream) {
    const float* x    = (const float*)d_in[0];   // [32,256,128,128]
    const float* w    = (const float*)d_in[1];   // [1,256,1,1] -> 256 floats
    const float* bias = (const float*)d_in[2];   // [1]
    float*       out  = (float*)d_out;           // [32,1]
    float*       scores = (float*)d_ws;          // 2 MiB scratch

    score_kernel<<<512, 256, 0, stream>>>(x, w, bias, scores);
    topk_mean_kernel<<<B_, 1024, 0, stream>>>(scores, out);
}

// Round 6
// 95.683 us; speedup vs baseline: 1.4408x; 1.0310x over previous
//
#include <hip/hip_runtime.h>
#include <hip/hip_bf16.h>
#include <stdint.h>

// Problem constants (from reference setup_inputs)
#define B_    32
#define C_    256
#define HW_   16384          // 128*128
#define K_TOP 1638           // int(16384 * 0.1)

typedef float f32x2 __attribute__((ext_vector_type(2)));
typedef float f32x4 __attribute__((ext_vector_type(4)));

// ---------------------------------------------------------------------------
// Kernel 1: scores[b, hw] = | sum_c x[b,c,hw] * w[c] + bias |
// - x is 512 MiB stream-once data: NON-TEMPORAL loads (no cache alloc; keeps
//   the 2 MiB scores buffer cache-resident for kernel 2).        [R3: -7 us]
// - unroll 8: 8 outstanding dwordx4/wave = 64 KiB in flight/CU, ~7x the
//   Little's-law need. unroll 16 measured WORSE (98.6 vs 95.9 us, R5) —
//   depth is not the limit; the stream runs at 96.5% of the measured
//   6.29 TB/s copy ceiling.                               [R5 post-mortem]
// - per-channel advance on the wave-uniform base pointer -> SADDR loads with
//   scalar base increments; w[c] uniform -> s_load; packed FMA via SGPR pair.
// NOTE (R4 post-mortem): do NOT fuse topk via last-block-done — device-scope
// release/acquire fences (L2 writeback+invalidate per block) cost ~40 us.
// ---------------------------------------------------------------------------
__global__ __launch_bounds__(256) void score_kernel(const float* __restrict__ x,
                                                    const float* __restrict__ w,
                                                    const float* __restrict__ bias,
                                                    float* __restrict__ scores) {
    const uint32_t tid  = blockIdx.x * 256u + threadIdx.x;   // 0 .. 131071
    const uint32_t bi   = tid >> 12;                         // batch
    const uint32_t p4   = (tid & 4095u) << 2;                // position*4
    const uint32_t toff = bi * (uint32_t)(C_ * HW_) + p4;    // element offset (fits 32b)

    const float* xc = x;                                     // wave-uniform, advances by HW_
    f32x2 a0 = {0.f, 0.f};
    f32x2 a1 = {0.f, 0.f};

    #pragma unroll 8
    for (int c = 0; c < C_; ++c) {
        const f32x4 v  = __builtin_nontemporal_load(
                             reinterpret_cast<const f32x4*>(xc + toff));
        const float wc = w[c];                               // uniform -> s_load
        const f32x2 wp = {wc, wc};                           // SGPR pair
        f32x2 lo = __builtin_shufflevector(v, v, 0, 1);
        f32x2 hi = __builtin_shufflevector(v, v, 2, 3);
        asm("v_pk_fma_f32 %0, %1, %2, %0" : "+v"(a0) : "v"(lo), "s"(wp));
        asm("v_pk_fma_f32 %0, %1, %2, %0" : "+v"(a1) : "v"(hi), "s"(wp));
        xc += HW_;
    }

    const float bb = bias[0];
    f32x4 o;
    o[0] = fabsf(a0[0] + bb);
    o[1] = fabsf(a0[1] + bb);
    o[2] = fabsf(a1[0] + bb);
    o[3] = fabsf(a1[1] + bb);
    *reinterpret_cast<f32x4*>(scores + (bi * (uint32_t)HW_ + p4)) = o;
}

// ---------------------------------------------------------------------------
// Wave-parallel crossing-bin finder. hist has NB bins (NB in {2048, 512});
// finds bin B s.t. suffix_count(B+1) < k <= suffix_count(B).
// ---------------------------------------------------------------------------
template <int NB>
__device__ __forceinline__ void find_crossing(const uint32_t* hist, int k,
                                              int* sh_bin, int* sh_k, int tid) {
    constexpr int G = NB >> 6;                      // bins per lane (32 or 8)
    if (tid < 64) {
        const int lane = tid;
        uint32_t gs = 0;
        #pragma unroll
        for (int i = 0; i < G; ++i) {
            const int j = (i + lane) & (G - 1);     // rotate to spread banks
            gs += hist[lane * G + j];
        }
        // suffix sum across 64 lanes
        uint32_t s = gs;
        #pragma unroll
        for (int off = 1; off < 64; off <<= 1) {
            uint32_t t = __shfl_down(s, off);
            s += (lane + off < 64) ? t : 0u;
        }
        uint32_t snext = __shfl_down(s, 1);
        if (lane == 63) snext = 0u;
        const bool mine = (s >= (uint32_t)k) && (snext < (uint32_t)k);
        const unsigned long long bal = __ballot(mine);
        const int g = __ffsll(bal) - 1;             // winning group (uniform)
        const uint32_t above_g = __shfl(snext, g);  // count strictly above group g

        // stage 2: suffix scan of the G bins inside group g
        uint32_t hv = (lane < G) ? hist[g * G + lane] : 0u;
        uint32_t s2 = hv;
        #pragma unroll
        for (int off = 1; off < G; off <<= 1) {
            uint32_t t = __shfl_down(s2, off);
            s2 += (lane + off < G) ? t : 0u;
        }
        uint32_t s2next = __shfl_down(s2, 1);
        if (lane >= G - 1) s2next = 0u;
        const bool mine2 = (lane < G) &&
                           (above_g + s2 >= (uint32_t)k) &&
                           (above_g + s2next < (uint32_t)k);
        if (mine2) {
            *sh_bin = g * G + lane;
            *sh_k   = k - (int)(above_g + s2next);
        }
    }
    __syncthreads();
}

// ---------------------------------------------------------------------------
// Kernel 2: per-batch exact top-K mean. One block (1024 thr, 16 waves) per
// batch; each thread keeps 16 values in registers for all 3 radix passes.
// Radix levels: bits 30:20 (2048 bins) -> 19:9 (2048) -> 8:0 (512, counts +
// sums; values in a final bin are bit-identical so float atomics are exact).
// ---------------------------------------------------------------------------
__global__ __launch_bounds__(1024) void topk_mean_kernel(const float* __restrict__ scores,
                                                         float* __restrict__ out) {
    const int tid = threadIdx.x;
    const int b   = blockIdx.x;

    __shared__ uint32_t hist[2048];
    __shared__ float    sumc[512];
    __shared__ float    red[16];
    __shared__ int      sh_bin, sh_k;

    const uint4* sv = reinterpret_cast<const uint4*>(scores) + (size_t)b * (HW_ / 4);
    uint32_t r[16];
    {
        uint4 q;
        q = sv[tid];        r[0]  = q.x; r[1]  = q.y; r[2]  = q.z; r[3]  = q.w;
        q = sv[tid + 1024]; r[4]  = q.x; r[5]  = q.y; r[6]  = q.z; r[7]  = q.w;
        q = sv[tid + 2048]; r[8]  = q.x; r[9]  = q.y; r[10] = q.z; r[11] = q.w;
        q = sv[tid + 3072]; r[12] = q.x; r[13] = q.y; r[14] = q.z; r[15] = q.w;
    }

    hist[tid] = 0u; hist[tid + 1024] = 0u;
    __syncthreads();

    // ---- pass A: bits 30:20 ----
    #pragma unroll
    for (int i = 0; i < 16; ++i) atomicAdd(&hist[r[i] >> 20], 1u);
    __syncthreads();
    find_crossing<2048>(hist, K_TOP, &sh_bin, &sh_k, tid);
    const uint32_t B1 = (uint32_t)sh_bin;
    const int      k1 = sh_k;
    __syncthreads();

    hist[tid] = 0u; hist[tid + 1024] = 0u;
    __syncthreads();

    // ---- pass B: bits 19:9 among prefix-B1; accumulate sum above B1 ----
    float sAbove = 0.f;
    #pragma unroll
    for (int i = 0; i < 16; ++i) {
        const uint32_t u  = r[i];
        const uint32_t b1 = u >> 20;
        if (b1 > B1)       sAbove += __uint_as_float(u);
        else if (b1 == B1) atomicAdd(&hist[(u >> 9) & 2047u], 1u);
    }
    __syncthreads();
    find_crossing<2048>(hist, k1, &sh_bin, &sh_k, tid);
    const uint32_t B2 = (uint32_t)sh_bin;
    const int      k2 = sh_k;
    __syncthreads();

    if (tid < 512) { hist[tid] = 0u; sumc[tid] = 0.f; }
    __syncthreads();

    // ---- pass C: bits 8:0 among prefix-(B1,B2); counts + exact sums ----
    #pragma unroll
    for (int i = 0; i < 16; ++i) {
        const uint32_t u = r[i];
        if ((u >> 20) == B1) {
            const uint32_t b2 = (u >> 9) & 2047u;
            if (b2 > B2) sAbove += __uint_as_float(u);
            else if (b2 == B2) {
                const uint32_t b3 = u & 511u;
                atomicAdd(&hist[b3], 1u);
                atomicAdd(&sumc[b3], __uint_as_float(u));
            }
        }
    }
    __syncthreads();
    find_crossing<512>(hist, k2, &sh_bin, &sh_k, tid);
    const uint32_t B3 = (uint32_t)sh_bin;
    const int      k3 = sh_k;
    __syncthreads();

    if (tid < 512 && tid > (int)B3) sAbove += sumc[tid];

    #pragma unroll
    for (int off = 32; off > 0; off >>= 1) sAbove += __shfl_down(sAbove, off);
    if ((tid & 63) == 0) red[tid >> 6] = sAbove;
    __syncthreads();

    if (tid == 0) {
        float tot = 0.f;
        #pragma unroll
        for (int i = 0; i < 16; ++i) tot += red[i];
        const float T = __uint_as_float((B1 << 20) | (B2 << 9) | B3);
        out[b] = (tot + (float)k3 * T) / (float)K_TOP;
    }
}

// ---------------------------------------------------------------------------
extern "C" void kernel_launch(void* const* d_in, const int* in_sizes, int n_in,
                              void* d_out, int out_size, void* d_ws, size_t ws_size,
                              hipStream_t stream) {
    const float* x    = (const float*)d_in[0];   // [32,256,128,128]
    const float* w    = (const float*)d_in[1];   // [1,256,1,1] -> 256 floats
    const float* bias = (const float*)d_in[2];   // [1]
    float*       out  = (float*)d_out;           // [32,1]
    float*       scores = (float*)d_ws;          // 2 MiB scratch

    score_kernel<<<512, 256, 0, stream>>>(x, w, bias, scores);
    topk_mean_kernel<<<B_, 1024, 0, stream>>>(scores, out);
}